// Round 1
// baseline (3904.670 us; speedup 1.0000x reference)
//
#include <hip/hip_runtime.h>

#define DEVI __device__ __forceinline__

typedef __bf16 bf16x8 __attribute__((ext_vector_type(8)));
typedef float f32x4 __attribute__((ext_vector_type(4)));

DEVI float bf2f(unsigned short u) {
    unsigned v = ((unsigned)u) << 16;
    float f;
    __builtin_memcpy(&f, &v, 4);
    return f;
}
DEVI unsigned short f2bf(float f) {
    unsigned u;
    __builtin_memcpy(&u, &f, 4);
    u = u + 0x7FFFu + ((u >> 16) & 1u);   // RNE
    return (unsigned short)(u >> 16);
}

DEVI void gl_lds16(const void* g, void* l) {
    __builtin_amdgcn_global_load_lds(
        (const __attribute__((address_space(1))) void*)(unsigned long long)g,
        (__attribute__((address_space(3))) void*)(unsigned)(unsigned long long)l,
        16, 0, 0);
}

// ---------------------------------------------------------------------------
// Weight conversion: wq/wk/wv (L,H,C,DH) fp32 -> wqkvt [L][3072][1024] bf16
// (row n = s*1024 + h*64 + d, transposed so K(=C) is contiguous)
// ---------------------------------------------------------------------------
__global__ __launch_bounds__(256) void conv_qkv(const float* __restrict__ w,
                                                unsigned short* __restrict__ out,
                                                int s) {
    __shared__ float tile[32][33];
    const int lh = blockIdx.z, l = lh >> 4, hh = lh & 15;
    const int c0 = blockIdx.y * 32, d0 = blockIdx.x * 32;
    const int tx = threadIdx.x, ty = threadIdx.y;
    const float* src = w + (size_t)(l * 16 + hh) * 1024 * 64;
#pragma unroll
    for (int i = 0; i < 4; i++)
        tile[ty + i * 8][tx] = src[(size_t)(c0 + ty + i * 8) * 64 + d0 + tx];
    __syncthreads();
    const size_t nbase = (size_t)l * 3072 + (size_t)s * 1024 + hh * 64 + d0;
#pragma unroll
    for (int i = 0; i < 4; i++)
        out[(nbase + ty + i * 8) * 1024 + c0 + tx] = f2bf(tile[tx][ty + i * 8]);
}

// Generic: in (Kd x N) fp32 (blockIdx.z-th matrix) -> out (N x Kd) bf16
__global__ __launch_bounds__(256) void transp_k(const float* __restrict__ in,
                                                unsigned short* __restrict__ out,
                                                int Kd, int N) {
    __shared__ float tile[32][33];
    const size_t mo = (size_t)blockIdx.z * Kd * N;
    const int k0 = blockIdx.y * 32, n0 = blockIdx.x * 32;
    const int tx = threadIdx.x, ty = threadIdx.y;
#pragma unroll
    for (int i = 0; i < 4; i++)
        tile[ty + i * 8][tx] = in[mo + (size_t)(k0 + ty + i * 8) * N + n0 + tx];
    __syncthreads();
#pragma unroll
    for (int i = 0; i < 4; i++)
        out[mo + (size_t)(n0 + ty + i * 8) * Kd + k0 + tx] = f2bf(tile[tx][ty + i * 8]);
}

// ---------------------------------------------------------------------------
// LayerNorm: fp32 in -> bf16 out (1024 cols, one block per row)
// ---------------------------------------------------------------------------
__global__ __launch_bounds__(256) void ln_k(const float* __restrict__ x,
                                            const float* __restrict__ g,
                                            const float* __restrict__ b,
                                            unsigned short* __restrict__ out) {
    const int row = blockIdx.x, tid = threadIdx.x;
    const float4 v = ((const float4*)(x + (size_t)row * 1024))[tid];
    float s = v.x + v.y + v.z + v.w;
    float s2 = v.x * v.x + v.y * v.y + v.z * v.z + v.w * v.w;
#pragma unroll
    for (int o = 32; o > 0; o >>= 1) {
        s += __shfl_down(s, o);
        s2 += __shfl_down(s2, o);
    }
    __shared__ float red[8];
    const int lane = tid & 63, wv = tid >> 6;
    if (lane == 0) { red[wv] = s; red[wv + 4] = s2; }
    __syncthreads();
    s = red[0] + red[1] + red[2] + red[3];
    s2 = red[4] + red[5] + red[6] + red[7];
    const float mu = s * (1.f / 1024.f);
    const float var = s2 * (1.f / 1024.f) - mu * mu;
    const float inv = rsqrtf(var + 1e-5f);
    const float4 gv = ((const float4*)g)[tid];
    const float4 bv = ((const float4*)b)[tid];
    union { unsigned short us[4]; uint2 u2; } pk;
    pk.us[0] = f2bf((v.x - mu) * inv * gv.x + bv.x);
    pk.us[1] = f2bf((v.y - mu) * inv * gv.y + bv.y);
    pk.us[2] = f2bf((v.z - mu) * inv * gv.z + bv.z);
    pk.us[3] = f2bf((v.w - mu) * inv * gv.w + bv.w);
    ((uint2*)(out + (size_t)row * 1024))[tid] = pk.u2;
}

// ---------------------------------------------------------------------------
// bf16 MFMA GEMM (m97 structure): out[M,N] = A[M,Kd] * Bt[N,Kd]^T (+bias,res,relu)
// 128x128 tile, BK=32, 4 waves (2x2), 16x16x32 MFMA, global_load_lds width16.
// M,N multiples of 128; Kd multiple of 32.
// ---------------------------------------------------------------------------
template <int OUT_BF16, int RELU, int HAS_RES>
__global__ __launch_bounds__(256) void gemm_k(const unsigned short* __restrict__ A,
                                              const unsigned short* __restrict__ Bt,
                                              const float* __restrict__ bias,
                                              const float* __restrict__ res,
                                              void* __restrict__ outp,
                                              int M, int N, int Kd) {
    __shared__ __align__(16) unsigned short As[128 * 32];
    __shared__ __align__(16) unsigned short Bs[128 * 32];
    const int tid = threadIdx.x;
    const int lane = tid & 63, w = tid >> 6;
    const int wr = w >> 1, wc = w & 1;
    const int m0 = blockIdx.y * 128, n0 = blockIdx.x * 128;

    f32x4 acc[4][4];
#pragma unroll
    for (int i = 0; i < 4; i++)
#pragma unroll
        for (int j = 0; j < 4; j++) acc[i][j] = (f32x4){0.f, 0.f, 0.f, 0.f};

    const int srow = tid >> 2;        // 0..63
    const int skg = (tid & 3) * 8;    // k sub-offset
    const unsigned short* ap = A + (size_t)(m0 + srow) * Kd + skg;
    const unsigned short* bp = Bt + (size_t)(n0 + srow) * Kd + skg;
    unsigned short* asw = &As[w * 512];
    unsigned short* bsw = &Bs[w * 512];
    const int lm = lane & 15, lk = (lane >> 4) * 8;

    for (int k0 = 0; k0 < Kd; k0 += 32) {
        gl_lds16(ap + k0, asw);
        gl_lds16(ap + (size_t)64 * Kd + k0, asw + 2048);
        gl_lds16(bp + k0, bsw);
        gl_lds16(bp + (size_t)64 * Kd + k0, bsw + 2048);
        __syncthreads();
        bf16x8 af[4], bfv[4];
#pragma unroll
        for (int mi = 0; mi < 4; mi++)
            af[mi] = *(const bf16x8*)&As[(wr * 64 + mi * 16 + lm) * 32 + lk];
#pragma unroll
        for (int ni = 0; ni < 4; ni++)
            bfv[ni] = *(const bf16x8*)&Bs[(wc * 64 + ni * 16 + lm) * 32 + lk];
#pragma unroll
        for (int mi = 0; mi < 4; mi++)
#pragma unroll
            for (int ni = 0; ni < 4; ni++)
                acc[mi][ni] = __builtin_amdgcn_mfma_f32_16x16x32_bf16(
                    af[mi], bfv[ni], acc[mi][ni], 0, 0, 0);
        __syncthreads();
    }

    const int lr4 = (lane >> 4) * 4;
#pragma unroll
    for (int mi = 0; mi < 4; mi++) {
#pragma unroll
        for (int ni = 0; ni < 4; ni++) {
#pragma unroll
            for (int rr = 0; rr < 4; rr++) {
                const int row = m0 + wr * 64 + mi * 16 + lr4 + rr;
                const int col = n0 + wc * 64 + ni * 16 + lm;
                float v = acc[mi][ni][rr];
                if (bias) v += bias[col];
                if (HAS_RES) v += res[(size_t)row * N + col];
                if (RELU) v = fmaxf(v, 0.f);
                if (OUT_BF16)
                    ((unsigned short*)outp)[(size_t)row * N + col] = f2bf(v);
                else
                    ((float*)outp)[(size_t)row * N + col] = v;
            }
        }
    }
}

// ---------------------------------------------------------------------------
// Flash attention, fp32 VALU. qkv: [T][3072] fp32 (q|k|v each 1024, col h*64+d).
// Grid: (T/64, H). Block 256 = 16x16 threads of 4x4 micro-tiles. Out: bf16 [T][1024].
// ---------------------------------------------------------------------------
__global__ __launch_bounds__(256) void attn_k(const float* __restrict__ qkv,
                                              unsigned short* __restrict__ O) {
    const int h = blockIdx.y;
    const int t0 = blockIdx.x * 64;
    const int tid = threadIdx.x;
    const int tr = tid >> 4, tc = tid & 15;
    __shared__ float Qs[64 * 68], Ks[64 * 68], Vs[64 * 68];   // pad: 17 float4 / row
    __shared__ unsigned short Ps[64 * 72];

    // stage Q (pre-scaled by 1/sqrt(64))
#pragma unroll
    for (int i = 0; i < 4; i++) {
        const int rr = (tid >> 4) + i * 16;
        const int cc = (tid & 15) * 4;
        float4 qv = *(const float4*)&qkv[(size_t)(t0 + rr) * 3072 + h * 64 + cc];
        qv.x *= 0.125f; qv.y *= 0.125f; qv.z *= 0.125f; qv.w *= 0.125f;
        *(float4*)&Qs[rr * 68 + cc] = qv;
    }

    float mrun[4], lrun[4];
    f32x4 acc[4];
#pragma unroll
    for (int i = 0; i < 4; i++) {
        mrun[i] = -1e30f;
        lrun[i] = 0.f;
        acc[i] = (f32x4){0.f, 0.f, 0.f, 0.f};
    }

    const int nt = blockIdx.x + 1;
    for (int kt = 0; kt < nt; ++kt) {
        const int s0 = kt * 64;
#pragma unroll
        for (int i = 0; i < 4; i++) {
            const int rr = (tid >> 4) + i * 16;
            const int cc = (tid & 15) * 4;
            *(float4*)&Ks[rr * 68 + cc] =
                *(const float4*)&qkv[(size_t)(s0 + rr) * 3072 + 1024 + h * 64 + cc];
            *(float4*)&Vs[rr * 68 + cc] =
                *(const float4*)&qkv[(size_t)(s0 + rr) * 3072 + 2048 + h * 64 + cc];
        }
        __syncthreads();

        // S = Q K^T  (rows tr*4.., cols tc*4..)
        float sc[4][4];
#pragma unroll
        for (int i = 0; i < 4; i++)
#pragma unroll
            for (int j = 0; j < 4; j++) sc[i][j] = 0.f;
        const float4* Q4 = (const float4*)Qs;
        const float4* K4 = (const float4*)Ks;
#pragma unroll 4
        for (int d4 = 0; d4 < 16; ++d4) {
            float4 qv[4], kv[4];
#pragma unroll
            for (int i = 0; i < 4; i++) qv[i] = Q4[(tr * 4 + i) * 17 + d4];
#pragma unroll
            for (int j = 0; j < 4; j++) kv[j] = K4[(tc * 4 + j) * 17 + d4];
#pragma unroll
            for (int i = 0; i < 4; i++)
#pragma unroll
                for (int j = 0; j < 4; j++)
                    sc[i][j] += qv[i].x * kv[j].x + qv[i].y * kv[j].y +
                                qv[i].z * kv[j].z + qv[i].w * kv[j].w;
        }
        // causal mask (only the diagonal tile can mask)
        if (s0 + 63 > t0) {
#pragma unroll
            for (int i = 0; i < 4; i++)
#pragma unroll
                for (int j = 0; j < 4; j++)
                    if (s0 + tc * 4 + j > t0 + tr * 4 + i) sc[i][j] = -1e30f;
        }
        // online softmax (rows owned by 16 lanes tc=0..15 -> shfl_xor reduce)
        float mloc[4];
#pragma unroll
        for (int i = 0; i < 4; i++)
            mloc[i] = fmaxf(fmaxf(sc[i][0], sc[i][1]), fmaxf(sc[i][2], sc[i][3]));
#pragma unroll
        for (int msk = 1; msk < 16; msk <<= 1)
#pragma unroll
            for (int i = 0; i < 4; i++)
                mloc[i] = fmaxf(mloc[i], __shfl_xor(mloc[i], msk));
        float rsum[4];
#pragma unroll
        for (int i = 0; i < 4; i++) {
            const float mnew = fmaxf(mrun[i], mloc[i]);
            const float sold = __expf(mrun[i] - mnew);
            mrun[i] = mnew;
            float rs = 0.f;
#pragma unroll
            for (int j = 0; j < 4; j++) {
                const float p = __expf(sc[i][j] - mnew);
                sc[i][j] = p;
                rs += p;
            }
            rsum[i] = rs;
            lrun[i] *= sold;
            acc[i] *= sold;
        }
#pragma unroll
        for (int msk = 1; msk < 16; msk <<= 1)
#pragma unroll
            for (int i = 0; i < 4; i++) rsum[i] += __shfl_xor(rsum[i], msk);
#pragma unroll
        for (int i = 0; i < 4; i++) lrun[i] += rsum[i];
        // write P tile (bf16)
#pragma unroll
        for (int i = 0; i < 4; i++) {
            union { unsigned short us[4]; uint2 u2; } pk;
#pragma unroll
            for (int j = 0; j < 4; j++) pk.us[j] = f2bf(sc[i][j]);
            *(uint2*)&Ps[(tr * 4 + i) * 72 + tc * 4] = pk.u2;
        }
        __syncthreads();

        // O += P V  (rows tr*4.., dims tc*4..)
        const float4* V4 = (const float4*)Vs;
#pragma unroll 4
        for (int c4 = 0; c4 < 16; ++c4) {
            float4 vv[4];
#pragma unroll
            for (int j = 0; j < 4; j++) vv[j] = V4[(c4 * 4 + j) * 17 + tc];
#pragma unroll
            for (int i = 0; i < 4; i++) {
                union { unsigned short us[4]; uint2 u2; } pk;
                pk.u2 = *(const uint2*)&Ps[(tr * 4 + i) * 72 + c4 * 4];
                const float p0 = bf2f(pk.us[0]), p1 = bf2f(pk.us[1]);
                const float p2 = bf2f(pk.us[2]), p3 = bf2f(pk.us[3]);
                f32x4 a = acc[i];
                a.x += p0 * vv[0].x + p1 * vv[1].x + p2 * vv[2].x + p3 * vv[3].x;
                a.y += p0 * vv[0].y + p1 * vv[1].y + p2 * vv[2].y + p3 * vv[3].y;
                a.z += p0 * vv[0].z + p1 * vv[1].z + p2 * vv[2].z + p3 * vv[3].z;
                a.w += p0 * vv[0].w + p1 * vv[1].w + p2 * vv[2].w + p3 * vv[3].w;
                acc[i] = a;
            }
        }
        __syncthreads();
    }

#pragma unroll
    for (int i = 0; i < 4; i++) {
        const float inv = 1.f / lrun[i];
        union { unsigned short us[4]; uint2 u2; } pk;
        pk.us[0] = f2bf(acc[i].x * inv);
        pk.us[1] = f2bf(acc[i].y * inv);
        pk.us[2] = f2bf(acc[i].z * inv);
        pk.us[3] = f2bf(acc[i].w * inv);
        *(uint2*)&O[(size_t)(t0 + tr * 4 + i) * 1024 + h * 64 + tc * 4] = pk.u2;
    }
}

// ---------------------------------------------------------------------------
// shift-right by K-1=3 rows and reshape to (512, 4096), emit bf16
// ---------------------------------------------------------------------------
__global__ __launch_bounds__(256) void shift_k(const float* __restrict__ x,
                                               unsigned short* __restrict__ xs) {
    const size_t e = ((size_t)blockIdx.x * 256 + threadIdx.x) * 4;  // over 512*4096
    const int trow = (int)(e >> 12);
    const int rem = (int)(e & 4095);
    const int j = rem >> 10, c = rem & 1023;
    const int tsrc = trow * 4 + j - 3;
    union { unsigned short us[4]; uint2 u2; } pk;
    if (tsrc >= 0) {
        const float4 v = *(const float4*)&x[(size_t)tsrc * 1024 + c];
        pk.us[0] = f2bf(v.x); pk.us[1] = f2bf(v.y);
        pk.us[2] = f2bf(v.z); pk.us[3] = f2bf(v.w);
    } else {
        pk.us[0] = pk.us[1] = pk.us[2] = pk.us[3] = 0;
    }
    *(uint2*)&xs[e] = pk.u2;
}

// x[t] += xp[t/4]  over (2048,1024)
__global__ __launch_bounds__(256) void upsamp_k(float* __restrict__ x,
                                                const float* __restrict__ xp) {
    const size_t e = ((size_t)blockIdx.x * 256 + threadIdx.x) * 4;
    const int t = (int)(e >> 10), c = (int)(e & 1023);
    float4 a = *(const float4*)&x[e];
    const float4 bq = *(const float4*)&xp[(size_t)(t >> 2) * 1024 + c];
    a.x += bq.x; a.y += bq.y; a.z += bq.z; a.w += bq.w;
    *(float4*)&x[e] = a;
}

// ---------------------------------------------------------------------------
extern "C" void kernel_launch(void* const* d_in, const int* in_sizes, int n_in,
                              void* d_out, int out_size, void* d_ws, size_t ws_size,
                              hipStream_t stream) {
    const float* x_in  = (const float*)d_in[0];
    const float* ln1_g = (const float*)d_in[1];
    const float* ln1_b = (const float*)d_in[2];
    const float* ln2_g = (const float*)d_in[3];
    const float* ln2_b = (const float*)d_in[4];
    const float* wq    = (const float*)d_in[5];
    const float* wk    = (const float*)d_in[6];
    const float* wv    = (const float*)d_in[7];
    const float* wo    = (const float*)d_in[8];
    const float* bo    = (const float*)d_in[9];
    const float* w1    = (const float*)d_in[10];
    const float* b1    = (const float*)d_in[11];
    const float* w2    = (const float*)d_in[12];
    const float* b2    = (const float*)d_in[13];
    const float* projw = (const float*)d_in[14];
    const float* projb = (const float*)d_in[15];

    char* ws = (char*)d_ws;
    size_t off = 0;
    auto alloc = [&](size_t bytes) {
        void* p = ws + off;
        off += (bytes + 255) & ~(size_t)255;
        return p;
    };
    unsigned short* wqkvt = (unsigned short*)alloc((size_t)6 * 3072 * 1024 * 2);
    unsigned short* wot   = (unsigned short*)alloc((size_t)6 * 1024 * 1024 * 2);
    unsigned short* w1t   = (unsigned short*)alloc((size_t)6 * 4096 * 1024 * 2);
    unsigned short* w2t   = (unsigned short*)alloc((size_t)6 * 1024 * 4096 * 2);
    unsigned short* pjt   = (unsigned short*)alloc((size_t)1024 * 4096 * 2);
    unsigned short* lnout = (unsigned short*)alloc((size_t)2048 * 1024 * 2);
    float*          qkvb  = (float*)alloc((size_t)2048 * 3072 * 4);
    unsigned short* obuf  = (unsigned short*)alloc((size_t)2048 * 1024 * 2);
    unsigned short* hbuf  = (unsigned short*)alloc((size_t)2048 * 4096 * 2);
    unsigned short* xsb   = (unsigned short*)alloc((size_t)512 * 4096 * 2);
    float*          xp    = (float*)alloc((size_t)512 * 1024 * 4);
    float* X = (float*)d_out;   // residual stream lives in d_out (fp32)

    // per-launch weight conversion (d_ws is re-poisoned each call)
    conv_qkv<<<dim3(2, 32, 96), dim3(32, 8), 0, stream>>>(wq, wqkvt, 0);
    conv_qkv<<<dim3(2, 32, 96), dim3(32, 8), 0, stream>>>(wk, wqkvt, 1);
    conv_qkv<<<dim3(2, 32, 96), dim3(32, 8), 0, stream>>>(wv, wqkvt, 2);
    transp_k<<<dim3(32, 32, 6),  dim3(32, 8), 0, stream>>>(wo, wot, 1024, 1024);
    transp_k<<<dim3(128, 32, 6), dim3(32, 8), 0, stream>>>(w1, w1t, 1024, 4096);
    transp_k<<<dim3(32, 128, 6), dim3(32, 8), 0, stream>>>(w2, w2t, 4096, 1024);
    transp_k<<<dim3(32, 128, 1), dim3(32, 8), 0, stream>>>(projw, pjt, 4096, 1024);

    hipMemcpyAsync(X, x_in, (size_t)2048 * 1024 * 4, hipMemcpyDeviceToDevice, stream);

    auto layer = [&](float* xb, int T, int i) {
        ln_k<<<T, 256, 0, stream>>>(xb, ln1_g + i * 1024, ln1_b + i * 1024, lnout);
        gemm_k<0, 0, 0><<<dim3(24, T / 128), 256, 0, stream>>>(
            lnout, wqkvt + (size_t)i * 3072 * 1024, nullptr, nullptr, qkvb, T, 3072, 1024);
        attn_k<<<dim3(T / 64, 16), 256, 0, stream>>>(qkvb, obuf);
        gemm_k<0, 0, 1><<<dim3(8, T / 128), 256, 0, stream>>>(
            obuf, wot + (size_t)i * 1024 * 1024, bo + i * 1024, xb, xb, T, 1024, 1024);
        ln_k<<<T, 256, 0, stream>>>(xb, ln2_g + i * 1024, ln2_b + i * 1024, lnout);
        gemm_k<1, 1, 0><<<dim3(32, T / 128), 256, 0, stream>>>(
            lnout, w1t + (size_t)i * 4096 * 1024, b1 + i * 4096, nullptr, hbuf, T, 4096, 1024);
        gemm_k<0, 0, 1><<<dim3(8, T / 128), 256, 0, stream>>>(
            hbuf, w2t + (size_t)i * 1024 * 4096, b2 + i * 1024, xb, xb, T, 1024, 4096);
    };

    layer(X, 2048, 0);
    layer(X, 2048, 1);

    shift_k<<<2048, 256, 0, stream>>>(X, xsb);
    gemm_k<0, 0, 0><<<dim3(8, 4), 256, 0, stream>>>(xsb, pjt, projb, nullptr, xp,
                                                    512, 1024, 4096);
    layer(xp, 512, 2);
    layer(xp, 512, 3);

    upsamp_k<<<2048, 256, 0, stream>>>(X, xp);

    layer(X, 2048, 4);
    layer(X, 2048, 5);
}